// Round 3
// baseline (53416.876 us; speedup 1.0000x reference)
//
#include <hip/hip_runtime.h>
#include <hip/hip_cooperative_groups.h>

namespace cg = cooperative_groups;

// 2-layer LSTM, S=512, B=32, H=1024, E=512.
// Round 2: persistent cooperative kernel, 256 blocks x 512 threads
// (1 block/CU guaranteed co-resident: needs only VGPR<=256, LDS 43.5KB).
// One grid.sync() per timestep (L0->L1 boundary only; L1->L0' is race-free:
// L0(s+1) reads only L0(s) data which is behind sync(s), and concurrent
// L1(s)/L0(s+1) writes touch disjoint addresses).
// Launch return IS checked; on failure fall back to the verified round-0
// per-step kernel path (1024 launches).
// All state lives in d_out's hiddens/cells regions; no workspace needed.

#define S_LEN 512
#define BATCH 32
#define HID   1024
#define EMB   512
#define KC    256
#define NBLK  256   // cooperative grid: 1 block per CU

__device__ __forceinline__ float sigmoidf_(float x) {
    return 1.0f / (1.0f + expf(-x));
}

// ---------------- persistent-kernel phase: 512 threads, 4 j-cols/block ------
// t = b + 32*jl + 128*ks ; b=batch row, jl=0..3 column-lane, ks=0..3 K-split.
// j = blockIdx.x*4 + jl covers 0..1023 with 256 blocks.
// Gate rows: i,f,g,o at j + g*1024. Math identical to verified round-0 kernel.
__device__ __forceinline__ void lstm_phase(
    float As[32][KC + 4], float red[512][5],
    const float* __restrict__ Wi, const float* __restrict__ Wh,
    const float* __restrict__ bi, const float* __restrict__ bh,
    const float* __restrict__ xsrc, const int* __restrict__ xidx, const int K1,
    const float* __restrict__ Hprev, const float* __restrict__ Cprev,
    float* __restrict__ Hout, float* __restrict__ Cout,
    float* __restrict__ Hout2)
{
    const int t  = threadIdx.x;
    const int b  = t & 31;
    const int jl = (t >> 5) & 3;
    const int ks = t >> 7;                       // 0..3
    const int j  = (blockIdx.x << 2) + jl;       // 0..1023

    const int Ktot = K1 + HID;
    const int NC   = Ktot / KC;                  // 6 (layer0) or 8 (layer1)

    float acc0 = 0.f, acc1 = 0.f, acc2 = 0.f, acc3 = 0.f;

    for (int c = 0; c < NC; ++c) {
        const int  k0  = c * KC;
        const bool isX = (k0 < K1);              // chunk boundaries align with K1

        // ---- stage A chunk (32 rows x KC floats) into LDS, coalesced ----
        #pragma unroll
        for (int i = 0; i < 4; ++i) {
            const int idx4 = t + (i << 9);       // 0..2047 float4 slots
            const int row  = idx4 >> 6;          // 0..31
            const int c4   = idx4 & 63;          // 0..63
            const float* src;
            if (isX) {
                const size_t r0 = xidx ? (size_t)xidx[row] : (size_t)row;
                src = xsrc + r0 * (size_t)K1 + k0;
            } else {
                src = Hprev + (size_t)row * HID + (k0 - K1);
            }
            const float4 v = *(const float4*)(src + (c4 << 2));
            *(float4*)&As[row][c4 << 2] = v;
        }
        __syncthreads();

        // ---- accumulate this thread's 64-wide sub-range of the chunk ----
        const float* W      = isX ? Wi : Wh;
        const int    stride = isX ? K1 : HID;
        const int    kw     = k0 + (ks << 6) - (isX ? 0 : K1);
        const float* w0 = W + (size_t)(j       ) * stride + kw;
        const float* w1 = W + (size_t)(j + 1024) * stride + kw;
        const float* w2 = W + (size_t)(j + 2048) * stride + kw;
        const float* w3 = W + (size_t)(j + 3072) * stride + kw;
        const float* a  = &As[b][ks << 6];

        #pragma unroll 4
        for (int kk = 0; kk < 64; kk += 4) {
            const float4 av = *(const float4*)(a + kk);
            float4 w;
            w = *(const float4*)(w0 + kk);
            acc0 = fmaf(av.x, w.x, acc0); acc0 = fmaf(av.y, w.y, acc0);
            acc0 = fmaf(av.z, w.z, acc0); acc0 = fmaf(av.w, w.w, acc0);
            w = *(const float4*)(w1 + kk);
            acc1 = fmaf(av.x, w.x, acc1); acc1 = fmaf(av.y, w.y, acc1);
            acc1 = fmaf(av.z, w.z, acc1); acc1 = fmaf(av.w, w.w, acc1);
            w = *(const float4*)(w2 + kk);
            acc2 = fmaf(av.x, w.x, acc2); acc2 = fmaf(av.y, w.y, acc2);
            acc2 = fmaf(av.z, w.z, acc2); acc2 = fmaf(av.w, w.w, acc2);
            w = *(const float4*)(w3 + kk);
            acc3 = fmaf(av.x, w.x, acc3); acc3 = fmaf(av.y, w.y, acc3);
            acc3 = fmaf(av.z, w.z, acc3); acc3 = fmaf(av.w, w.w, acc3);
        }
        __syncthreads();
    }

    // ---- reduce the 4 K-splits, then pointwise LSTM ----
    red[t][0] = acc0; red[t][1] = acc1; red[t][2] = acc2; red[t][3] = acc3;
    __syncthreads();

    if (t < 128) {  // ks==0 threads: one per (b, jl) pair of this block
        float tot[4];
        #pragma unroll
        for (int g = 0; g < 4; ++g) {
            const int r = j + (g << 10);
            tot[g] = red[t][g] + red[t + 128][g] + red[t + 256][g] + red[t + 384][g]
                   + bi[r] + bh[r];
        }
        const float ig = sigmoidf_(tot[0]);
        const float fg = sigmoidf_(tot[1]);
        const float gg = tanhf(tot[2]);
        const float og = sigmoidf_(tot[3]);
        const size_t o  = (size_t)b * HID + j;
        const float  cp = Cprev[o];
        const float  cn = fg * cp + ig * gg;
        const float  hn = og * tanhf(cn);
        Cout[o] = cn;
        Hout[o] = hn;
        if (Hout2) Hout2[o] = hn;
    }
    __syncthreads();
}

__global__ __launch_bounds__(512)
void lstm_persistent(const int* __restrict__ x, const float* __restrict__ embed,
                     const float* __restrict__ Wi0, const float* __restrict__ Wh0,
                     const float* __restrict__ bi0, const float* __restrict__ bh0,
                     const float* __restrict__ Wi1, const float* __restrict__ Wh1,
                     const float* __restrict__ bi1, const float* __restrict__ bh1,
                     const float* __restrict__ h0in, const float* __restrict__ c0in,
                     float* __restrict__ outputs, float* __restrict__ hiddens,
                     float* __restrict__ cells)
{
    __shared__ float As[32][KC + 4];
    __shared__ float red[512][5];

    cg::grid_group grid = cg::this_grid();
    const size_t BH = (size_t)BATCH * HID;

    for (int s = 0; s < S_LEN; ++s) {
        const float* Hp0 = s ? hiddens + ((size_t)(s - 1) * 2 + 0) * BH : h0in;
        const float* Cp0 = s ? cells   + ((size_t)(s - 1) * 2 + 0) * BH : c0in;
        float* H0o = hiddens + ((size_t)s * 2 + 0) * BH;
        float* C0o = cells   + ((size_t)s * 2 + 0) * BH;
        lstm_phase(As, red, Wi0, Wh0, bi0, bh0,
                   embed, x + (size_t)s * BATCH, EMB,
                   Hp0, Cp0, H0o, C0o, nullptr);

        grid.sync();   // publish h0[s] to all blocks/XCDs

        const float* Hp1 = s ? hiddens + ((size_t)(s - 1) * 2 + 1) * BH : h0in + BH;
        const float* Cp1 = s ? cells   + ((size_t)(s - 1) * 2 + 1) * BH : c0in + BH;
        float* H1o = hiddens + ((size_t)s * 2 + 1) * BH;
        float* C1o = cells   + ((size_t)s * 2 + 1) * BH;
        lstm_phase(As, red, Wi1, Wh1, bi1, bh1,
                   H0o, nullptr, HID,
                   Hp1, Cp1, H1o, C1o, outputs + (size_t)s * BH);
        // no sync here: L0(s+1) reads only data published at sync(s), and
        // concurrent L1(s)/L0(s+1) work touches disjoint addresses.
    }
}

// ---------------- fallback: verified round-0 per-step kernel ----------------
__global__ __launch_bounds__(256)
void lstm_step(const float* __restrict__ Wi, const float* __restrict__ Wh,
               const float* __restrict__ bi, const float* __restrict__ bh,
               const float* __restrict__ xsrc, const int* __restrict__ xidx, int K1,
               const float* __restrict__ Hprev, const float* __restrict__ Cprev,
               float* __restrict__ Hout, float* __restrict__ Cout,
               float* __restrict__ Hout2)
{
    __shared__ float As[32][KC + 4];
    __shared__ float red[256][5];

    const int t  = threadIdx.x;
    const int b  = t & 31;
    const int jl = (t >> 5) & 1;
    const int ks = t >> 6;
    const int j  = (blockIdx.x << 1) + jl;

    const int Ktot = K1 + HID;
    const int NC   = Ktot / KC;

    float acc0 = 0.f, acc1 = 0.f, acc2 = 0.f, acc3 = 0.f;

    for (int c = 0; c < NC; ++c) {
        const int  k0  = c * KC;
        const bool isX = (k0 < K1);

        #pragma unroll
        for (int i = 0; i < 8; ++i) {
            const int idx4 = t + (i << 8);
            const int row  = idx4 >> 6;
            const int c4   = idx4 & 63;
            const float* src;
            if (isX) {
                const size_t r0 = xidx ? (size_t)xidx[row] : (size_t)row;
                src = xsrc + r0 * (size_t)K1 + k0;
            } else {
                src = Hprev + (size_t)row * HID + (k0 - K1);
            }
            const float4 v = *(const float4*)(src + (c4 << 2));
            *(float4*)&As[row][c4 << 2] = v;
        }
        __syncthreads();

        const float* W      = isX ? Wi : Wh;
        const int    stride = isX ? K1 : HID;
        const int    kw     = k0 + (ks << 6) - (isX ? 0 : K1);
        const float* w0 = W + (size_t)(j       ) * stride + kw;
        const float* w1 = W + (size_t)(j + 1024) * stride + kw;
        const float* w2 = W + (size_t)(j + 2048) * stride + kw;
        const float* w3 = W + (size_t)(j + 3072) * stride + kw;
        const float* a  = &As[b][ks << 6];

        #pragma unroll 4
        for (int kk = 0; kk < 64; kk += 4) {
            const float4 av = *(const float4*)(a + kk);
            float4 w;
            w = *(const float4*)(w0 + kk);
            acc0 = fmaf(av.x, w.x, acc0); acc0 = fmaf(av.y, w.y, acc0);
            acc0 = fmaf(av.z, w.z, acc0); acc0 = fmaf(av.w, w.w, acc0);
            w = *(const float4*)(w1 + kk);
            acc1 = fmaf(av.x, w.x, acc1); acc1 = fmaf(av.y, w.y, acc1);
            acc1 = fmaf(av.z, w.z, acc1); acc1 = fmaf(av.w, w.w, acc1);
            w = *(const float4*)(w2 + kk);
            acc2 = fmaf(av.x, w.x, acc2); acc2 = fmaf(av.y, w.y, acc2);
            acc2 = fmaf(av.z, w.z, acc2); acc2 = fmaf(av.w, w.w, acc2);
            w = *(const float4*)(w3 + kk);
            acc3 = fmaf(av.x, w.x, acc3); acc3 = fmaf(av.y, w.y, acc3);
            acc3 = fmaf(av.z, w.z, acc3); acc3 = fmaf(av.w, w.w, acc3);
        }
        __syncthreads();
    }

    red[t][0] = acc0; red[t][1] = acc1; red[t][2] = acc2; red[t][3] = acc3;
    __syncthreads();

    if (t < 64) {
        float tot[4];
        #pragma unroll
        for (int g = 0; g < 4; ++g) {
            const int r = j + (g << 10);
            tot[g] = red[t][g] + red[t + 64][g] + red[t + 128][g] + red[t + 192][g]
                   + bi[r] + bh[r];
        }
        const float ig = sigmoidf_(tot[0]);
        const float fg = sigmoidf_(tot[1]);
        const float gg = tanhf(tot[2]);
        const float og = sigmoidf_(tot[3]);
        const size_t o  = (size_t)b * HID + j;
        const float  cp = Cprev[o];
        const float  cn = fg * cp + ig * gg;
        const float  hn = og * tanhf(cn);
        Cout[o] = cn;
        Hout[o] = hn;
        if (Hout2) Hout2[o] = hn;
    }
}

extern "C" void kernel_launch(void* const* d_in, const int* in_sizes, int n_in,
                              void* d_out, int out_size, void* d_ws, size_t ws_size,
                              hipStream_t stream)
{
    (void)in_sizes; (void)n_in; (void)out_size; (void)d_ws; (void)ws_size;

    const int*   x     = (const int*)  d_in[0];
    const float* embed = (const float*)d_in[1];
    const float* Wi0   = (const float*)d_in[2];
    const float* Wh0   = (const float*)d_in[3];
    const float* bi0   = (const float*)d_in[4];
    const float* bh0   = (const float*)d_in[5];
    const float* Wi1   = (const float*)d_in[6];
    const float* Wh1   = (const float*)d_in[7];
    const float* bi1   = (const float*)d_in[8];
    const float* bh1   = (const float*)d_in[9];
    const float* h0in  = (const float*)d_in[10];
    const float* c0in  = (const float*)d_in[11];

    float* out     = (float*)d_out;
    const size_t BH = (size_t)BATCH * HID;              // 32768
    float* outputs = out;                               // (S,1,B,H)
    float* hiddens = out + (size_t)S_LEN * BH;          // (S,L,B,H)
    float* cells   = out + 3 * (size_t)S_LEN * BH;      // (S,L,B,H)

    void* args[] = {
        (void*)&x, (void*)&embed,
        (void*)&Wi0, (void*)&Wh0, (void*)&bi0, (void*)&bh0,
        (void*)&Wi1, (void*)&Wh1, (void*)&bi1, (void*)&bh1,
        (void*)&h0in, (void*)&c0in,
        (void*)&outputs, (void*)&hiddens, (void*)&cells
    };
    hipError_t e = hipLaunchCooperativeKernel((void*)lstm_persistent,
                                              dim3(NBLK), dim3(512), args, 0, stream);
    if (e != hipSuccess) {
        (void)hipGetLastError();   // clear sticky error, use fallback path
        for (int s = 0; s < S_LEN; ++s) {
            const float* Hp0 = s ? hiddens + ((size_t)(s - 1) * 2 + 0) * BH : h0in;
            const float* Cp0 = s ? cells   + ((size_t)(s - 1) * 2 + 0) * BH : c0in;
            float* H0o = hiddens + ((size_t)s * 2 + 0) * BH;
            float* C0o = cells   + ((size_t)s * 2 + 0) * BH;
            lstm_step<<<512, 256, 0, stream>>>(Wi0, Wh0, bi0, bh0,
                                               embed, x + (size_t)s * BATCH, EMB,
                                               Hp0, Cp0, H0o, C0o, nullptr);

            const float* Hp1 = s ? hiddens + ((size_t)(s - 1) * 2 + 1) * BH : h0in + BH;
            const float* Cp1 = s ? cells   + ((size_t)(s - 1) * 2 + 1) * BH : c0in + BH;
            float* H1o = hiddens + ((size_t)s * 2 + 1) * BH;
            float* C1o = cells   + ((size_t)s * 2 + 1) * BH;
            lstm_step<<<512, 256, 0, stream>>>(Wi1, Wh1, bi1, bh1,
                                               H0o, nullptr, HID,
                                               Hp1, Cp1, H1o, C1o, outputs + (size_t)s * BH);
        }
    }
}

// Round 4
// 13290.919 us; speedup vs baseline: 4.0191x; 4.0191x over previous
//
#include <hip/hip_runtime.h>
#include <hip/hip_cooperative_groups.h>

namespace cg = cooperative_groups;

// 2-layer LSTM, S=512, B=32, H=1024, E=512 — MFMA + register-stationary weights.
//
// Round-3 diagnosis: 16.3 GB HBM fetch/dispatch = weights re-streamed every
// step at 323 GB/s == the entire runtime. Fix: weights live in VGPRs as bf16
// MFMA B-fragments for all 512 steps.
//
// Decomposition: 128 blocks x 512 threads (8 waves, 1 block/CU).
//   Block owns 8 j-columns (J0 = blockIdx*8) x 4 gates = 32 gate-rows/layer
//   = 2 MFMA N-tiles. Batch 32 = 2 M-tiles. K split 8-way across waves
//   (L0: Ktot=1536 -> 6 frags/wave; L1: 2048 -> 8 frags/wave), partial C
//   reduced through LDS. mfma_f32_16x16x32_bf16, f32 accumulate.
// h-recurrence: bf16 workspace tiled [kg][b] in 16B units == exactly the
//   A-fragment read pattern (lane l reads unit kg*32 + mt*16 + (l&15)) ->
//   coalesced 256B groups. Ping-pong buffers per layer; 1 grid.sync()/step
//   (schedule verified correct in round 3).
// Embedding slice staged per step through LDS (f32->bf16 RNE on the fly).
// c-recurrence in registers of the 32 pointwise threads; f32 h/c/outputs
// written to d_out as before.

#define S_LEN 512
#define BATCH 32
#define HID   1024
#define EMB   512
#define NBLK  128
#define NTHR  512

typedef short  bf16x8 __attribute__((ext_vector_type(8)));
typedef float  f32x4  __attribute__((ext_vector_type(4)));

union U8 { bf16x8 v; unsigned short us[8]; uint4 u4; };

__device__ __forceinline__ unsigned short f2bf(float f) {   // RNE f32->bf16
    unsigned u = __float_as_uint(f);
    u += 0x7fffu + ((u >> 16) & 1u);
    return (unsigned short)(u >> 16);
}

__device__ __forceinline__ uint4 pack8(float4 lo, float4 hi) {
    U8 r;
    r.us[0] = f2bf(lo.x); r.us[1] = f2bf(lo.y); r.us[2] = f2bf(lo.z); r.us[3] = f2bf(lo.w);
    r.us[4] = f2bf(hi.x); r.us[5] = f2bf(hi.y); r.us[6] = f2bf(hi.z); r.us[7] = f2bf(hi.w);
    return r.u4;
}

__device__ __forceinline__ f32x4 mfma16(bf16x8 a, bf16x8 b, f32x4 c) {
    return __builtin_amdgcn_mfma_f32_16x16x32_bf16(a, b, c, 0, 0, 0);
}

__device__ __forceinline__ float sigm(float x) {
    return 1.0f / (1.0f + __expf(-x));
}

__global__ __launch_bounds__(NTHR, 2)
void lstm_mfma(const int* __restrict__ x, const float* __restrict__ embed,
               const float* __restrict__ Wi0, const float* __restrict__ Wh0,
               const float* __restrict__ bi0, const float* __restrict__ bh0,
               const float* __restrict__ Wi1, const float* __restrict__ Wh1,
               const float* __restrict__ bi1, const float* __restrict__ bh1,
               const float* __restrict__ h0in, const float* __restrict__ c0in,
               float* __restrict__ outputs, float* __restrict__ hiddens,
               float* __restrict__ cells, uint4* __restrict__ ws)
{
    __shared__ uint4 sEmb[64 * 33];        // emb A-tiles [kg 0..63][b 0..31], +1 unit pad/kg
    __shared__ f32x4 sRed[8][4][64];       // per-wave partial C tiles
    __shared__ float sGates[32][33];       // reduced gates [b][n 0..31]
    __shared__ float sBias[2][8][4];       // bi+bh per (layer, jj, gate)

    const int tid  = threadIdx.x;
    const int lane = tid & 63;
    const int wv   = tid >> 6;             // 0..7 = K-split
    const int bx   = blockIdx.x;

    uint4* h0ws[2] = { ws,         ws + 4096 };
    uint4* h1ws[2] = { ws + 8192,  ws + 12288 };

    // ---- one-time: weight B-fragments into registers (f32 -> bf16 RNE) ----
    // B-frag (16x16x32): lane l elem e = B[k=(l>>4)*8+e][n=l&15] = W[row(n)][k].
    // row(n) = gate(n>>2)*1024 + bx*8 + nt*4 + (n&3).
    bf16x8 w0[2][6], w1[2][8];
    {
        const int n    = lane & 15;
        const int ko   = (lane >> 4) << 3;
        const int rbase = ((n >> 2) << 10) + (bx << 3) + (n & 3);
        #pragma unroll
        for (int nt = 0; nt < 2; ++nt) {
            const int r = rbase + (nt << 2);
            #pragma unroll
            for (int kf = 0; kf < 6; ++kf) {
                const int k = wv * 192 + kf * 32 + ko;
                const float* src = (k < EMB) ? Wi0 + (size_t)r * EMB + k
                                             : Wh0 + (size_t)r * HID + (k - EMB);
                U8 t; t.u4 = pack8(*(const float4*)src, *(const float4*)(src + 4));
                w0[nt][kf] = t.v;
            }
            #pragma unroll
            for (int kf = 0; kf < 8; ++kf) {
                const int k = wv * 256 + kf * 32 + ko;
                const float* src = (k < HID) ? Wi1 + (size_t)r * HID + k
                                             : Wh1 + (size_t)r * HID + (k - HID);
                U8 t; t.u4 = pack8(*(const float4*)src, *(const float4*)(src + 4));
                w1[nt][kf] = t.v;
            }
        }
    }

    // ---- one-time: h0/c0 -> tiled bf16 ws (ping buffer 1) ----
    {
        const int gt = bx * NTHR + tid;
        if (gt < 8192) {                   // 2 layers x 128 kg x 32 b
            const int layer = gt >> 12, kg = (gt >> 5) & 127, b = gt & 31;
            const float* src = h0in + (((size_t)layer << 5) + b) * HID + (kg << 3);
            uint4* dst = layer ? h1ws[1] : h0ws[1];
            dst[(kg << 5) + b] = pack8(*(const float4*)src, *(const float4*)(src + 4));
        }
    }
    // ---- one-time: bias sums into LDS; c-state into pointwise-thread regs ----
    if (tid < 8) {
        #pragma unroll
        for (int g = 0; g < 4; ++g) {
            const int r = (g << 10) + (bx << 3) + tid;
            sBias[0][tid][g] = bi0[r] + bh0[r];
            sBias[1][tid][g] = bi1[r] + bh1[r];
        }
    }
    float c0r[8], c1r[8];
    if (tid < 32) {
        #pragma unroll
        for (int jj = 0; jj < 8; ++jj) {
            const int jg = (bx << 3) + jj;
            c0r[jj] = c0in[(size_t)tid * HID + jg];
            c1r[jj] = c0in[(size_t)(BATCH + tid) * HID + jg];
        }
    }

    cg::grid_group grid = cg::this_grid();
    grid.sync();                           // publish ws prepass to all blocks

    const size_t BH = (size_t)BATCH * HID; // 32768

    for (int s = 0; s < S_LEN; ++s) {
        // ================= LAYER 0 =================
        // stage emb A-part: 32 rows x 512 -> bf16 tiles in LDS
        const int* xs = x + (s << 5);
        #pragma unroll
        for (int it = 0; it < 4; ++it) {
            const int idx = tid + (it << 9);          // 0..2047
            const int b = idx >> 6, kg = idx & 63;    // wave reads one emb row
            const float* src = embed + (size_t)xs[b] * EMB + (kg << 3);
            sEmb[kg * 33 + b] = pack8(*(const float4*)src, *(const float4*)(src + 4));
        }
        const uint4* h0p = h0ws[(s + 1) & 1];
        __syncthreads();

        f32x4 acc[2][2] = {{{0.f,0.f,0.f,0.f},{0.f,0.f,0.f,0.f}},
                           {{0.f,0.f,0.f,0.f},{0.f,0.f,0.f,0.f}}};
        #pragma unroll
        for (int kf = 0; kf < 6; ++kf) {
            const int kfg = wv * 6 + kf;              // global K-frag 0..47
            bf16x8 a0, a1;
            if (kfg < 16) {                           // emb region (k < 512)
                const int u = ((kfg << 2) + (lane >> 4)) * 33 + (lane & 15);
                U8 t0; t0.u4 = sEmb[u];      a0 = t0.v;
                U8 t1; t1.u4 = sEmb[u + 16]; a1 = t1.v;
            } else {                                  // h0_prev region
                const int u = (((kfg - 16) << 2) + (lane >> 4)) * 32 + (lane & 15);
                U8 t0; t0.u4 = h0p[u];       a0 = t0.v;
                U8 t1; t1.u4 = h0p[u + 16];  a1 = t1.v;
            }
            acc[0][0] = mfma16(a0, w0[0][kf], acc[0][0]);
            acc[0][1] = mfma16(a0, w0[1][kf], acc[0][1]);
            acc[1][0] = mfma16(a1, w0[0][kf], acc[1][0]);
            acc[1][1] = mfma16(a1, w0[1][kf], acc[1][1]);
        }
        #pragma unroll
        for (int mt = 0; mt < 2; ++mt)
            #pragma unroll
            for (int nt = 0; nt < 2; ++nt)
                sRed[wv][(mt << 1) + nt][lane] = acc[mt][nt];
        __syncthreads();

        if (tid < 256) {                   // K-split reduction -> gates LDS
            const int tile = tid >> 6, l = tid & 63;
            f32x4 sum = sRed[0][tile][l];
            #pragma unroll
            for (int w = 1; w < 8; ++w) sum += sRed[w][tile][l];
            const int mt = tile >> 1, nt = tile & 1;
            const int mb = (mt << 4) + ((l >> 4) << 2), nn = (nt << 4) + (l & 15);
            sGates[mb + 0][nn] = sum[0];
            sGates[mb + 1][nn] = sum[1];
            sGates[mb + 2][nn] = sum[2];
            sGates[mb + 3][nn] = sum[3];
        }
        __syncthreads();

        {   // pointwise L0: thread tid<32 owns batch row tid, 8 j-columns
            float* H0o = hiddens + (size_t)(s << 1) * BH;
            float* C0o = cells   + (size_t)(s << 1) * BH;
            if (tid < 32) {
                U8 hb;
                #pragma unroll
                for (int jj = 0; jj < 8; ++jj) {
                    const int nb = ((jj >> 2) << 4) + (jj & 3);
                    const float ii = sigm (sGates[tid][nb]      + sBias[0][jj][0]);
                    const float ff = sigm (sGates[tid][nb + 4]  + sBias[0][jj][1]);
                    const float gg = tanhf(sGates[tid][nb + 8]  + sBias[0][jj][2]);
                    const float oo = sigm (sGates[tid][nb + 12] + sBias[0][jj][3]);
                    const float cn = ff * c0r[jj] + ii * gg;
                    c0r[jj] = cn;
                    const float hn = oo * tanhf(cn);
                    const int jg = (bx << 3) + jj;
                    C0o[(size_t)tid * HID + jg] = cn;
                    H0o[(size_t)tid * HID + jg] = hn;
                    hb.us[jj] = f2bf(hn);
                }
                h0ws[s & 1][(bx << 5) + tid] = hb.u4;  // block's 8 j == tile kg=bx
            }
        }
        grid.sync();                       // publish h0[s] to all blocks

        // ================= LAYER 1 =================
        const uint4* h0c = h0ws[s & 1];
        const uint4* h1p = h1ws[(s + 1) & 1];
        f32x4 acc1[2][2] = {{{0.f,0.f,0.f,0.f},{0.f,0.f,0.f,0.f}},
                            {{0.f,0.f,0.f,0.f},{0.f,0.f,0.f,0.f}}};
        #pragma unroll
        for (int kf = 0; kf < 8; ++kf) {
            const int kfg = (wv << 3) + kf;           // 0..63
            const uint4* src = (kfg < 32) ? h0c : h1p;
            const int kgb = (kfg < 32) ? (kfg << 2) : ((kfg - 32) << 2);
            const int u = (kgb + (lane >> 4)) * 32 + (lane & 15);
            U8 t0; t0.u4 = src[u];      const bf16x8 a0 = t0.v;
            U8 t1; t1.u4 = src[u + 16]; const bf16x8 a1 = t1.v;
            acc1[0][0] = mfma16(a0, w1[0][kf], acc1[0][0]);
            acc1[0][1] = mfma16(a0, w1[1][kf], acc1[0][1]);
            acc1[1][0] = mfma16(a1, w1[0][kf], acc1[1][0]);
            acc1[1][1] = mfma16(a1, w1[1][kf], acc1[1][1]);
        }
        #pragma unroll
        for (int mt = 0; mt < 2; ++mt)
            #pragma unroll
            for (int nt = 0; nt < 2; ++nt)
                sRed[wv][(mt << 1) + nt][lane] = acc1[mt][nt];
        __syncthreads();

        if (tid < 256) {
            const int tile = tid >> 6, l = tid & 63;
            f32x4 sum = sRed[0][tile][l];
            #pragma unroll
            for (int w = 1; w < 8; ++w) sum += sRed[w][tile][l];
            const int mt = tile >> 1, nt = tile & 1;
            const int mb = (mt << 4) + ((l >> 4) << 2), nn = (nt << 4) + (l & 15);
            sGates[mb + 0][nn] = sum[0];
            sGates[mb + 1][nn] = sum[1];
            sGates[mb + 2][nn] = sum[2];
            sGates[mb + 3][nn] = sum[3];
        }
        __syncthreads();

        {   // pointwise L1 (+ outputs)
            float* H1o = hiddens + (size_t)((s << 1) + 1) * BH;
            float* C1o = cells   + (size_t)((s << 1) + 1) * BH;
            float* Oo  = outputs + (size_t)s * BH;
            if (tid < 32) {
                U8 hb;
                #pragma unroll
                for (int jj = 0; jj < 8; ++jj) {
                    const int nb = ((jj >> 2) << 4) + (jj & 3);
                    const float ii = sigm (sGates[tid][nb]      + sBias[1][jj][0]);
                    const float ff = sigm (sGates[tid][nb + 4]  + sBias[1][jj][1]);
                    const float gg = tanhf(sGates[tid][nb + 8]  + sBias[1][jj][2]);
                    const float oo = sigm (sGates[tid][nb + 12] + sBias[1][jj][3]);
                    const float cn = ff * c1r[jj] + ii * gg;
                    c1r[jj] = cn;
                    const float hn = oo * tanhf(cn);
                    const int jg = (bx << 3) + jj;
                    C1o[(size_t)tid * HID + jg] = cn;
                    H1o[(size_t)tid * HID + jg] = hn;
                    Oo [(size_t)tid * HID + jg] = hn;
                    hb.us[jj] = f2bf(hn);
                }
                h1ws[s & 1][(bx << 5) + tid] = hb.u4;
            }
        }
        // no trailing sync needed: next-iter stage barrier orders LDS reuse,
        // grid.sync(s+1) orders cross-block h1 reads.
    }
}

// ---------------- fallback: verified round-0 per-step kernel ----------------
#define KC 256
__global__ __launch_bounds__(256)
void lstm_step(const float* __restrict__ Wi, const float* __restrict__ Wh,
               const float* __restrict__ bi, const float* __restrict__ bh,
               const float* __restrict__ xsrc, const int* __restrict__ xidx, int K1,
               const float* __restrict__ Hprev, const float* __restrict__ Cprev,
               float* __restrict__ Hout, float* __restrict__ Cout,
               float* __restrict__ Hout2)
{
    __shared__ float As[32][KC + 4];
    __shared__ float red[256][5];

    const int t  = threadIdx.x;
    const int b  = t & 31;
    const int jl = (t >> 5) & 1;
    const int ks = t >> 6;
    const int j  = (blockIdx.x << 1) + jl;

    const int Ktot = K1 + HID;
    const int NC   = Ktot / KC;

    float acc0 = 0.f, acc1 = 0.f, acc2 = 0.f, acc3 = 0.f;

    for (int c = 0; c < NC; ++c) {
        const int  k0  = c * KC;
        const bool isX = (k0 < K1);

        #pragma unroll
        for (int i = 0; i < 8; ++i) {
            const int idx4 = t + (i << 8);
            const int row  = idx4 >> 6;
            const int c4   = idx4 & 63;
            const float* src;
            if (isX) {
                const size_t r0 = xidx ? (size_t)xidx[row] : (size_t)row;
                src = xsrc + r0 * (size_t)K1 + k0;
            } else {
                src = Hprev + (size_t)row * HID + (k0 - K1);
            }
            *(float4*)&As[row][c4 << 2] = *(const float4*)(src + (c4 << 2));
        }
        __syncthreads();

        const float* W      = isX ? Wi : Wh;
        const int    stride = isX ? K1 : HID;
        const int    kw     = k0 + (ks << 6) - (isX ? 0 : K1);
        const float* w0 = W + (size_t)(j       ) * stride + kw;
        const float* w1 = W + (size_t)(j + 1024) * stride + kw;
        const float* w2 = W + (size_t)(j + 2048) * stride + kw;
        const float* w3 = W + (size_t)(j + 3072) * stride + kw;
        const float* a  = &As[b][ks << 6];

        #pragma unroll 4
        for (int kk = 0; kk < 64; kk += 4) {
            const float4 av = *(const float4*)(a + kk);
            float4 w;
            w = *(const float4*)(w0 + kk);
            acc0 = fmaf(av.x, w.x, acc0); acc0 = fmaf(av.y, w.y, acc0);
            acc0 = fmaf(av.z, w.z, acc0); acc0 = fmaf(av.w, w.w, acc0);
            w = *(const float4*)(w1 + kk);
            acc1 = fmaf(av.x, w.x, acc1); acc1 = fmaf(av.y, w.y, acc1);
            acc1 = fmaf(av.z, w.z, acc1); acc1 = fmaf(av.w, w.w, acc1);
            w = *(const float4*)(w2 + kk);
            acc2 = fmaf(av.x, w.x, acc2); acc2 = fmaf(av.y, w.y, acc2);
            acc2 = fmaf(av.z, w.z, acc2); acc2 = fmaf(av.w, w.w, acc2);
            w = *(const float4*)(w3 + kk);
            acc3 = fmaf(av.x, w.x, acc3); acc3 = fmaf(av.y, w.y, acc3);
            acc3 = fmaf(av.z, w.z, acc3); acc3 = fmaf(av.w, w.w, acc3);
        }
        __syncthreads();
    }

    red[t][0] = acc0; red[t][1] = acc1; red[t][2] = acc2; red[t][3] = acc3;
    __syncthreads();

    if (t < 64) {
        float tot[4];
        #pragma unroll
        for (int g = 0; g < 4; ++g) {
            const int r = j + (g << 10);
            tot[g] = red[t][g] + red[t + 64][g] + red[t + 128][g] + red[t + 192][g]
                   + bi[r] + bh[r];
        }
        const float ig = 1.f / (1.f + expf(-tot[0]));
        const float fg = 1.f / (1.f + expf(-tot[1]));
        const float gg = tanhf(tot[2]);
        const float og = 1.f / (1.f + expf(-tot[3]));
        const size_t o  = (size_t)b * HID + j;
        const float  cp = Cprev[o];
        const float  cn = fg * cp + ig * gg;
        const float  hn = og * tanhf(cn);
        Cout[o] = cn;
        Hout[o] = hn;
        if (Hout2) Hout2[o] = hn;
    }
}

extern "C" void kernel_launch(void* const* d_in, const int* in_sizes, int n_in,
                              void* d_out, int out_size, void* d_ws, size_t ws_size,
                              hipStream_t stream)
{
    (void)in_sizes; (void)n_in; (void)out_size;

    const int*   x     = (const int*)  d_in[0];
    const float* embed = (const float*)d_in[1];
    const float* Wi0   = (const float*)d_in[2];
    const float* Wh0   = (const float*)d_in[3];
    const float* bi0   = (const float*)d_in[4];
    const float* bh0   = (const float*)d_in[5];
    const float* Wi1   = (const float*)d_in[6];
    const float* Wh1   = (const float*)d_in[7];
    const float* bi1   = (const float*)d_in[8];
    const float* bh1   = (const float*)d_in[9];
    const float* h0in  = (const float*)d_in[10];
    const float* c0in  = (const float*)d_in[11];

    float* out     = (float*)d_out;
    const size_t BH = (size_t)BATCH * HID;              // 32768
    float* outputs = out;                               // (S,1,B,H)
    float* hiddens = out + (size_t)S_LEN * BH;          // (S,L,B,H)
    float* cells   = out + 3 * (size_t)S_LEN * BH;      // (S,L,B,H)
    uint4* ws      = (uint4*)d_ws;                      // 4 x 64KB h-tile buffers

    bool coop_ok = (ws_size >= 4 * 65536);
    if (coop_ok) {
        void* args[] = {
            (void*)&x, (void*)&embed,
            (void*)&Wi0, (void*)&Wh0, (void*)&bi0, (void*)&bh0,
            (void*)&Wi1, (void*)&Wh1, (void*)&bi1, (void*)&bh1,
            (void*)&h0in, (void*)&c0in,
            (void*)&outputs, (void*)&hiddens, (void*)&cells, (void*)&ws
        };
        hipError_t e = hipLaunchCooperativeKernel((void*)lstm_mfma,
                                                  dim3(NBLK), dim3(NTHR), args, 0, stream);
        if (e != hipSuccess) { (void)hipGetLastError(); coop_ok = false; }
    }
    if (!coop_ok) {
        for (int s = 0; s < S_LEN; ++s) {
            const float* Hp0 = s ? hiddens + ((size_t)(s - 1) * 2 + 0) * BH : h0in;
            const float* Cp0 = s ? cells   + ((size_t)(s - 1) * 2 + 0) * BH : c0in;
            float* H0o = hiddens + ((size_t)s * 2 + 0) * BH;
            float* C0o = cells   + ((size_t)s * 2 + 0) * BH;
            lstm_step<<<512, 256, 0, stream>>>(Wi0, Wh0, bi0, bh0,
                                               embed, x + (size_t)s * BATCH, EMB,
                                               Hp0, Cp0, H0o, C0o, nullptr);

            const float* Hp1 = s ? hiddens + ((size_t)(s - 1) * 2 + 1) * BH : h0in + BH;
            const float* Cp1 = s ? cells   + ((size_t)(s - 1) * 2 + 1) * BH : c0in + BH;
            float* H1o = hiddens + ((size_t)s * 2 + 1) * BH;
            float* C1o = cells   + ((size_t)s * 2 + 1) * BH;
            lstm_step<<<512, 256, 0, stream>>>(Wi1, Wh1, bi1, bh1,
                                               H0o, nullptr, HID,
                                               Hp1, Cp1, H1o, C1o, outputs + (size_t)s * BH);
        }
    }
}

// Round 5
// 4972.096 us; speedup vs baseline: 10.7433x; 2.6731x over previous
//
#include <hip/hip_runtime.h>
#include <hip/hip_cooperative_groups.h>

namespace cg = cooperative_groups;

// 2-layer LSTM, S=512, B=32, H=1024, E=512 — MFMA, register-stationary weights,
// fine-grained arrive/wait barriers (no grid.sync in the steady loop).
//
// Round-4 diagnosis: 26.6 us/step with all pipes idle = grid.sync fence cost
// (per-block L2 wb+inv across 8 XCDs) + serialized phases. Fixes:
//  * h-state exchanged via AGENT-SCOPE 8B atomics (bypass L2, coherent at LLC)
//    + per-step arrival counters -> no cache maintenance at all in the loop.
//  * emb A-tiles for ALL steps precomputed once in ws (kills x128-redundant
//    per-step gather; L2 stays warm since nothing invalidates it).
//  * pointwise on 256 threads (was 32); fast tanh/sigmoid via v_exp+v_rcp.
// MFMA fragment layout / K-split-8 / LDS reduction identical to round 4
// (verified). Fallbacks: no-embT staging if ws small; per-step kernels if
// cooperative launch fails or ws tiny.

#define S_LEN 512
#define BATCH 32
#define HID   1024
#define EMB   512
#define NBLK  128
#define NTHR  512

typedef short  bf16x8 __attribute__((ext_vector_type(8)));
typedef float  f32x4  __attribute__((ext_vector_type(4)));

union U8  { bf16x8 v; unsigned short us[8]; uint4 u4; unsigned long long ull[2]; };

__device__ __forceinline__ unsigned short f2bf(float f) {   // RNE f32->bf16
    unsigned u = __float_as_uint(f);
    u += 0x7fffu + ((u >> 16) & 1u);
    return (unsigned short)(u >> 16);
}

__device__ __forceinline__ uint4 pack8(float4 lo, float4 hi) {
    U8 r;
    r.us[0] = f2bf(lo.x); r.us[1] = f2bf(lo.y); r.us[2] = f2bf(lo.z); r.us[3] = f2bf(lo.w);
    r.us[4] = f2bf(hi.x); r.us[5] = f2bf(hi.y); r.us[6] = f2bf(hi.z); r.us[7] = f2bf(hi.w);
    return r.u4;
}

__device__ __forceinline__ f32x4 mfma16(bf16x8 a, bf16x8 b, f32x4 c) {
    return __builtin_amdgcn_mfma_f32_16x16x32_bf16(a, b, c, 0, 0, 0);
}

// agent-scope (LLC-coherent, L2-bypass) 16B load/store as 2x8B atomics
__device__ __forceinline__ U8 ld_ws16(const uint4* p) {
    const unsigned long long* q = (const unsigned long long*)p;
    U8 r;
    r.ull[0] = __hip_atomic_load(q,     __ATOMIC_RELAXED, __HIP_MEMORY_SCOPE_AGENT);
    r.ull[1] = __hip_atomic_load(q + 1, __ATOMIC_RELAXED, __HIP_MEMORY_SCOPE_AGENT);
    return r;
}
__device__ __forceinline__ void st_ws16(uint4* p, U8 v) {
    unsigned long long* q = (unsigned long long*)p;
    __hip_atomic_store(q,     v.ull[0], __ATOMIC_RELAXED, __HIP_MEMORY_SCOPE_AGENT);
    __hip_atomic_store(q + 1, v.ull[1], __ATOMIC_RELAXED, __HIP_MEMORY_SCOPE_AGENT);
}

__device__ __forceinline__ float sigm(float x) {
    return __builtin_amdgcn_rcpf(1.0f + __expf(-x));
}
__device__ __forceinline__ float tanh_fast(float x) {
    const float xc = fminf(fmaxf(x, -15.f), 15.f);
    const float t  = __expf(2.f * xc);
    return (t - 1.f) * __builtin_amdgcn_rcpf(t + 1.f);
}

__device__ __forceinline__ void spin_ge(const int* p, int target) {
    while (__hip_atomic_load(p, __ATOMIC_RELAXED, __HIP_MEMORY_SCOPE_AGENT) < target)
        __builtin_amdgcn_s_sleep(2);
}

__global__ __launch_bounds__(NTHR, 2)
void lstm_mfma(const int* __restrict__ x, const float* __restrict__ embed,
               const float* __restrict__ Wi0, const float* __restrict__ Wh0,
               const float* __restrict__ bi0, const float* __restrict__ bh0,
               const float* __restrict__ Wi1, const float* __restrict__ Wh1,
               const float* __restrict__ bi1, const float* __restrict__ bh1,
               const float* __restrict__ h0in, const float* __restrict__ c0in,
               float* __restrict__ outputs, float* __restrict__ hiddens,
               float* __restrict__ cells, uint4* __restrict__ ws,
               const uint4* __restrict__ embT)
{
    __shared__ uint4  sEmb[64 * 33];       // fallback emb staging (embT==null)
    __shared__ f32x4  sRed[8][4][64];      // per-wave partial C tiles
    __shared__ float  sGates[32][33];      // reduced gates [b][n]
    __shared__ float  sBias[2][8][4];
    __shared__ unsigned short sHex[32][8]; // h bf16 exchange for tile pack

    const int tid  = threadIdx.x;
    const int lane = tid & 63;
    const int wv   = tid >> 6;             // 0..7 = K-split
    const int bx   = blockIdx.x;

    uint4* h0ws[2] = { ws,         ws + 4096 };
    uint4* h1ws[2] = { ws + 8192,  ws + 12288 };
    int*   f0      = (int*)(ws + 16384);   // arrive0[s] at f0[s<<4]
    int*   f1      = f0 + 8192;            // arrive1[s] at f1[s<<4]

    // ---- one-time: weight B-fragments into registers (verified layout) ----
    bf16x8 w0[2][6], w1[2][8];
    {
        const int n    = lane & 15;
        const int ko   = (lane >> 4) << 3;
        const int rbase = ((n >> 2) << 10) + (bx << 3) + (n & 3);
        #pragma unroll
        for (int nt = 0; nt < 2; ++nt) {
            const int r = rbase + (nt << 2);
            #pragma unroll
            for (int kf = 0; kf < 6; ++kf) {
                const int k = wv * 192 + kf * 32 + ko;
                const float* src = (k < EMB) ? Wi0 + (size_t)r * EMB + k
                                             : Wh0 + (size_t)r * HID + (k - EMB);
                U8 t; t.u4 = pack8(*(const float4*)src, *(const float4*)(src + 4));
                w0[nt][kf] = t.v;
            }
            #pragma unroll
            for (int kf = 0; kf < 8; ++kf) {
                const int k = wv * 256 + kf * 32 + ko;
                const float* src = (k < HID) ? Wi1 + (size_t)r * HID + k
                                             : Wh1 + (size_t)r * HID + (k - HID);
                U8 t; t.u4 = pack8(*(const float4*)src, *(const float4*)(src + 4));
                w1[nt][kf] = t.v;
            }
        }
    }

    const int gt = bx * NTHR + tid;
    // ---- one-time: zero flags ----
    if (gt < 16384) ((int*)(ws + 16384))[gt] = 0;
    // ---- one-time: h0/c0 -> tiled bf16 ws (ping buffer 1) ----
    if (gt < 8192) {                       // 2 layers x 128 kg x 32 b
        const int layer = gt >> 12, kg = (gt >> 5) & 127, b = gt & 31;
        const float* src = h0in + (((size_t)layer << 5) + b) * HID + (kg << 3);
        uint4* dst = layer ? h1ws[1] : h0ws[1];
        dst[(kg << 5) + b] = pack8(*(const float4*)src, *(const float4*)(src + 4));
    }
    // ---- one-time: all-step emb A-tiles (if ws has room) ----
    if (embT) {
        uint4* eT = (uint4*)embT;
        #pragma unroll
        for (int it = 0; it < 16; ++it) {
            const int e  = gt + (it << 16);            // 0..2^20-1
            const int s  = e >> 11, kg = (e >> 5) & 63, b = e & 31;
            const float* src = embed + (size_t)x[(s << 5) + b] * EMB + (kg << 3);
            eT[e] = pack8(*(const float4*)src, *(const float4*)(src + 4));
        }
    }
    if (tid < 8) {
        #pragma unroll
        for (int g = 0; g < 4; ++g) {
            const int r = (g << 10) + (bx << 3) + tid;
            sBias[0][tid][g] = bi0[r] + bh0[r];
            sBias[1][tid][g] = bi1[r] + bh1[r];
        }
    }
    // ---- c-state: one (b, jj) column pair per thread (t<256) ----
    const int pb  = tid & 31;              // batch row
    const int pjj = tid >> 5;              // 0..7 (valid when tid<256)
    const int pjg = (bx << 3) + pjj;
    float c0r = 0.f, c1r = 0.f;
    if (tid < 256) {
        c0r = c0in[(size_t)pb * HID + pjg];
        c1r = c0in[(size_t)(BATCH + pb) * HID + pjg];
    }

    cg::grid_group grid = cg::this_grid();
    grid.sync();                           // publish prepass (full fence, once)

    const size_t BH = (size_t)BATCH * HID;

    for (int s = 0; s < S_LEN; ++s) {
        // ================= LAYER 0: gates = emb(s)@Wi0 + h0(s-1)@Wh0 ========
        const uint4* h0p = h0ws[(s + 1) & 1];
        if (!embT) {                       // fallback: stage emb via LDS
            const int* xs = x + (s << 5);
            #pragma unroll
            for (int it = 0; it < 4; ++it) {
                const int idx = tid + (it << 9);
                const int b = idx >> 6, kg = idx & 63;
                const float* src = embed + (size_t)xs[b] * EMB + (kg << 3);
                sEmb[kg * 33 + b] = pack8(*(const float4*)src, *(const float4*)(src + 4));
            }
            __syncthreads();
        }

        f32x4 acc[2][2] = {{{0.f,0.f,0.f,0.f},{0.f,0.f,0.f,0.f}},
                           {{0.f,0.f,0.f,0.f},{0.f,0.f,0.f,0.f}}};
        #pragma unroll
        for (int kf = 0; kf < 6; ++kf) {
            const int kfg = wv * 6 + kf;              // 0..47
            bf16x8 a0, a1;
            if (kfg < 16) {                           // emb region
                if (embT) {
                    const int u = ((kfg << 2) + (lane >> 4)) * 32 + (lane & 15);
                    const uint4* eT = embT + ((size_t)s << 11);
                    U8 t0; t0.u4 = eT[u];      a0 = t0.v;
                    U8 t1; t1.u4 = eT[u + 16]; a1 = t1.v;
                } else {
                    const int u = ((kfg << 2) + (lane >> 4)) * 33 + (lane & 15);
                    U8 t0; t0.u4 = sEmb[u];      a0 = t0.v;
                    U8 t1; t1.u4 = sEmb[u + 16]; a1 = t1.v;
                }
            } else {                                  // h0(s-1), coherent reads
                const int u = (((kfg - 16) << 2) + (lane >> 4)) * 32 + (lane & 15);
                a0 = ld_ws16(&h0p[u]).v;
                a1 = ld_ws16(&h0p[u + 16]).v;
            }
            acc[0][0] = mfma16(a0, w0[0][kf], acc[0][0]);
            acc[0][1] = mfma16(a0, w0[1][kf], acc[0][1]);
            acc[1][0] = mfma16(a1, w0[0][kf], acc[1][0]);
            acc[1][1] = mfma16(a1, w0[1][kf], acc[1][1]);
        }
        #pragma unroll
        for (int mt = 0; mt < 2; ++mt)
            #pragma unroll
            for (int nt = 0; nt < 2; ++nt)
                sRed[wv][(mt << 1) + nt][lane] = acc[mt][nt];
        __syncthreads();

        if (tid < 256) {                   // K-split reduction -> gates LDS
            const int tile = tid >> 6, l = tid & 63;
            f32x4 sum = sRed[0][tile][l];
            #pragma unroll
            for (int w = 1; w < 8; ++w) sum += sRed[w][tile][l];
            const int mt = tile >> 1, nt = tile & 1;
            const int mb = (mt << 4) + ((l >> 4) << 2), nn = (nt << 4) + (l & 15);
            sGates[mb + 0][nn] = sum[0];
            sGates[mb + 1][nn] = sum[1];
            sGates[mb + 2][nn] = sum[2];
            sGates[mb + 3][nn] = sum[3];
        }
        __syncthreads();

        {   // pointwise L0 on 256 threads: thread = (b, jj)
            float* H0o = hiddens + (size_t)(s << 1) * BH;
            float* C0o = cells   + (size_t)(s << 1) * BH;
            if (tid < 256) {
                const int nb = ((pjj >> 2) << 4) + (pjj & 3);
                const float ii = sigm     (sGates[pb][nb]      + sBias[0][pjj][0]);
                const float ff = sigm     (sGates[pb][nb + 4]  + sBias[0][pjj][1]);
                const float gg = tanh_fast(sGates[pb][nb + 8]  + sBias[0][pjj][2]);
                const float oo = sigm     (sGates[pb][nb + 12] + sBias[0][pjj][3]);
                const float cn = ff * c0r + ii * gg;
                c0r = cn;
                const float hn = oo * tanh_fast(cn);
                C0o[(size_t)pb * HID + pjg] = cn;
                H0o[(size_t)pb * HID + pjg] = hn;
                sHex[pb][pjj] = f2bf(hn);
            }
        }
        __syncthreads();
        if (tid < 32) {                    // pack + publish h0(s) tile
            U8 hb;
            #pragma unroll
            for (int jj = 0; jj < 8; ++jj) hb.us[jj] = sHex[tid][jj];
            st_ws16(&h0ws[s & 1][(bx << 5) + tid], hb);
        }
        asm volatile("s_waitcnt vmcnt(0)" ::: "memory");
        if (tid == 0) atomicAdd(&f0[s << 4], 1);

        // ================= wait: h1(s-1) [early], h0(s) [critical] ==========
        if (tid == 0) {
            if (s) spin_ge(&f1[(s - 1) << 4], NBLK);
            spin_ge(&f0[s << 4], NBLK);
        }
        __syncthreads();

        // ================= LAYER 1: gates = h0(s)@Wi1 + h1(s-1)@Wh1 =========
        const uint4* h0c = h0ws[s & 1];
        const uint4* h1p = h1ws[(s + 1) & 1];
        f32x4 acc1[2][2] = {{{0.f,0.f,0.f,0.f},{0.f,0.f,0.f,0.f}},
                            {{0.f,0.f,0.f,0.f},{0.f,0.f,0.f,0.f}}};
        #pragma unroll
        for (int kf = 0; kf < 8; ++kf) {
            const int kfg = (wv << 3) + kf;           // 0..63
            const uint4* src = (kfg < 32) ? h0c : h1p;
            const int kgb = (kfg < 32) ? (kfg << 2) : ((kfg - 32) << 2);
            const int u = (kgb + (lane >> 4)) * 32 + (lane & 15);
            const bf16x8 a0 = ld_ws16(&src[u]).v;
            const bf16x8 a1 = ld_ws16(&src[u + 16]).v;
            acc1[0][0] = mfma16(a0, w1[0][kf], acc1[0][0]);
            acc1[0][1] = mfma16(a0, w1[1][kf], acc1[0][1]);
            acc1[1][0] = mfma16(a1, w1[0][kf], acc1[1][0]);
            acc1[1][1] = mfma16(a1, w1[1][kf], acc1[1][1]);
        }
        #pragma unroll
        for (int mt = 0; mt < 2; ++mt)
            #pragma unroll
            for (int nt = 0; nt < 2; ++nt)
                sRed[wv][(mt << 1) + nt][lane] = acc1[mt][nt];
        __syncthreads();

        if (tid < 256) {
            const int tile = tid >> 6, l = tid & 63;
            f32x4 sum = sRed[0][tile][l];
            #pragma unroll
            for (int w = 1; w < 8; ++w) sum += sRed[w][tile][l];
            const int mt = tile >> 1, nt = tile & 1;
            const int mb = (mt << 4) + ((l >> 4) << 2), nn = (nt << 4) + (l & 15);
            sGates[mb + 0][nn] = sum[0];
            sGates[mb + 1][nn] = sum[1];
            sGates[mb + 2][nn] = sum[2];
            sGates[mb + 3][nn] = sum[3];
        }
        __syncthreads();

        {   // pointwise L1 (+ outputs)
            float* H1o = hiddens + (size_t)((s << 1) + 1) * BH;
            float* C1o = cells   + (size_t)((s << 1) + 1) * BH;
            float* Oo  = outputs + (size_t)s * BH;
            if (tid < 256) {
                const int nb = ((pjj >> 2) << 4) + (pjj & 3);
                const float ii = sigm     (sGates[pb][nb]      + sBias[1][pjj][0]);
                const float ff = sigm     (sGates[pb][nb + 4]  + sBias[1][pjj][1]);
                const float gg = tanh_fast(sGates[pb][nb + 8]  + sBias[1][pjj][2]);
                const float oo = sigm     (sGates[pb][nb + 12] + sBias[1][pjj][3]);
                const float cn = ff * c1r + ii * gg;
                c1r = cn;
                const float hn = oo * tanh_fast(cn);
                C1o[(size_t)pb * HID + pjg] = cn;
                H1o[(size_t)pb * HID + pjg] = hn;
                Oo [(size_t)pb * HID + pjg] = hn;
                sHex[pb][pjj] = f2bf(hn);
            }
        }
        __syncthreads();
        if (tid < 32) {
            U8 hb;
            #pragma unroll
            for (int jj = 0; jj < 8; ++jj) hb.us[jj] = sHex[tid][jj];
            st_ws16(&h1ws[s & 1][(bx << 5) + tid], hb);
        }
        asm volatile("s_waitcnt vmcnt(0)" ::: "memory");
        if (tid == 0) atomicAdd(&f1[s << 4], 1);
        // next iter's L0 reads h0(s): already guaranteed by wait0(s) above.
    }
}

// ---------------- fallback: verified round-0 per-step kernel ----------------
#define KC 256
__global__ __launch_bounds__(256)
void lstm_step(const float* __restrict__ Wi, const float* __restrict__ Wh,
               const float* __restrict__ bi, const float* __restrict__ bh,
               const float* __restrict__ xsrc, const int* __restrict__ xidx, int K1,
               const float* __restrict__ Hprev, const float* __restrict__ Cprev,
               float* __restrict__ Hout, float* __restrict__ Cout,
               float* __restrict__ Hout2)
{
    __shared__ float As[32][KC + 4];
    __shared__ float red[256][5];

    const int t  = threadIdx.x;
    const int b  = t & 31;
    const int jl = (t >> 5) & 1;
    const int ks = t >> 6;
    const int j  = (blockIdx.x << 1) + jl;

    const int Ktot = K1 + HID;
    const int NC   = Ktot / KC;

    float acc0 = 0.f, acc1 = 0.f, acc2 = 0.f, acc3 = 0.f;

    for (int c = 0; c < NC; ++c) {
        const int  k0  = c * KC;
        const bool isX = (k0 < K1);

        #pragma unroll
        for (int i = 0; i < 8; ++i) {
            const int idx4 = t + (i << 8);
            const int row  = idx4 >> 6;
            const int c4   = idx4 & 63;
            const float* src;
            if (isX) {
                const size_t r0 = xidx ? (size_t)xidx[row] : (size_t)row;
                src = xsrc + r0 * (size_t)K1 + k0;
            } else {
                src = Hprev + (size_t)row * HID + (k0 - K1);
            }
            *(float4*)&As[row][c4 << 2] = *(const float4*)(src + (c4 << 2));
        }
        __syncthreads();

        const float* W      = isX ? Wi : Wh;
        const int    stride = isX ? K1 : HID;
        const int    kw     = k0 + (ks << 6) - (isX ? 0 : K1);
        const float* w0 = W + (size_t)(j       ) * stride + kw;
        const float* w1 = W + (size_t)(j + 1024) * stride + kw;
        const float* w2 = W + (size_t)(j + 2048) * stride + kw;
        const float* w3 = W + (size_t)(j + 3072) * stride + kw;
        const float* a  = &As[b][ks << 6];

        #pragma unroll 4
        for (int kk = 0; kk < 64; kk += 4) {
            const float4 av = *(const float4*)(a + kk);
            float4 w;
            w = *(const float4*)(w0 + kk);
            acc0 = fmaf(av.x, w.x, acc0); acc0 = fmaf(av.y, w.y, acc0);
            acc0 = fmaf(av.z, w.z, acc0); acc0 = fmaf(av.w, w.w, acc0);
            w = *(const float4*)(w1 + kk);
            acc1 = fmaf(av.x, w.x, acc1); acc1 = fmaf(av.y, w.y, acc1);
            acc1 = fmaf(av.z, w.z, acc1); acc1 = fmaf(av.w, w.w, acc1);
            w = *(const float4*)(w2 + kk);
            acc2 = fmaf(av.x, w.x, acc2); acc2 = fmaf(av.y, w.y, acc2);
            acc2 = fmaf(av.z, w.z, acc2); acc2 = fmaf(av.w, w.w, acc2);
            w = *(const float4*)(w3 + kk);
            acc3 = fmaf(av.x, w.x, acc3); acc3 = fmaf(av.y, w.y, acc3);
            acc3 = fmaf(av.z, w.z, acc3); acc3 = fmaf(av.w, w.w, acc3);
        }
        __syncthreads();
    }

    red[t][0] = acc0; red[t][1] = acc1; red[t][2] = acc2; red[t][3] = acc3;
    __syncthreads();

    if (t < 64) {
        float tot[4];
        #pragma unroll
        for (int g = 0; g < 4; ++g) {
            const int r = j + (g << 10);
            tot[g] = red[t][g] + red[t + 64][g] + red[t + 128][g] + red[t + 192][g]
                   + bi[r] + bh[r];
        }
        const float ig = 1.f / (1.f + expf(-tot[0]));
        const float fg = 1.f / (1.f + expf(-tot[1]));
        const float gg = tanhf(tot[2]);
        const float og = 1.f / (1.f + expf(-tot[3]));
        const size_t o  = (size_t)b * HID + j;
        const float  cp = Cprev[o];
        const float  cn = fg * cp + ig * gg;
        const float  hn = og * tanhf(cn);
        Cout[o] = cn;
        Hout[o] = hn;
        if (Hout2) Hout2[o] = hn;
    }
}

extern "C" void kernel_launch(void* const* d_in, const int* in_sizes, int n_in,
                              void* d_out, int out_size, void* d_ws, size_t ws_size,
                              hipStream_t stream)
{
    (void)in_sizes; (void)n_in; (void)out_size;

    const int*   x     = (const int*)  d_in[0];
    const float* embed = (const float*)d_in[1];
    const float* Wi0   = (const float*)d_in[2];
    const float* Wh0   = (const float*)d_in[3];
    const float* bi0   = (const float*)d_in[4];
    const float* bh0   = (const float*)d_in[5];
    const float* Wi1   = (const float*)d_in[6];
    const float* Wh1   = (const float*)d_in[7];
    const float* bi1   = (const float*)d_in[8];
    const float* bh1   = (const float*)d_in[9];
    const float* h0in  = (const float*)d_in[10];
    const float* c0in  = (const float*)d_in[11];

    float* out     = (float*)d_out;
    const size_t BH = (size_t)BATCH * HID;              // 32768
    float* outputs = out;                               // (S,1,B,H)
    float* hiddens = out + (size_t)S_LEN * BH;          // (S,L,B,H)
    float* cells   = out + 3 * (size_t)S_LEN * BH;      // (S,L,B,H)
    uint4* ws      = (uint4*)d_ws;

    // ws layout (bytes): [0,256K) h tiles | [256K,320K) flags | [320K,+16M) embT
    const size_t NEED_BASE = 327680;
    const size_t NEED_EMBT = 327680 + (size_t)S_LEN * 2048 * 16;
    const uint4* embT = (ws_size >= NEED_EMBT) ? ws + 20480 : nullptr;

    bool coop_ok = (ws_size >= NEED_BASE);
    if (coop_ok) {
        void* args[] = {
            (void*)&x, (void*)&embed,
            (void*)&Wi0, (void*)&Wh0, (void*)&bi0, (void*)&bh0,
            (void*)&Wi1, (void*)&Wh1, (void*)&bi1, (void*)&bh1,
            (void*)&h0in, (void*)&c0in,
            (void*)&outputs, (void*)&hiddens, (void*)&cells,
            (void*)&ws, (void*)&embT
        };
        hipError_t e = hipLaunchCooperativeKernel((void*)lstm_mfma,
                                                  dim3(NBLK), dim3(NTHR), args, 0, stream);
        if (e != hipSuccess) { (void)hipGetLastError(); coop_ok = false; }
    }
    if (!coop_ok) {
        for (int s = 0; s < S_LEN; ++s) {
            const float* Hp0 = s ? hiddens + ((size_t)(s - 1) * 2 + 0) * BH : h0in;
            const float* Cp0 = s ? cells   + ((size_t)(s - 1) * 2 + 0) * BH : c0in;
            float* H0o = hiddens + ((size_t)s * 2 + 0) * BH;
            float* C0o = cells   + ((size_t)s * 2 + 0) * BH;
            lstm_step<<<512, 256, 0, stream>>>(Wi0, Wh0, bi0, bh0,
                                               embed, x + (size_t)s * BATCH, EMB,
                                               Hp0, Cp0, H0o, C0o, nullptr);

            const float* Hp1 = s ? hiddens + ((size_t)(s - 1) * 2 + 1) * BH : h0in + BH;
            const float* Cp1 = s ? cells   + ((size_t)(s - 1) * 2 + 1) * BH : c0in + BH;
            float* H1o = hiddens + ((size_t)s * 2 + 1) * BH;
            float* C1o = cells   + ((size_t)s * 2 + 1) * BH;
            lstm_step<<<512, 256, 0, stream>>>(Wi1, Wh1, bi1, bh1,
                                               H0o, nullptr, HID,
                                               Hp1, Cp1, H1o, C1o, outputs + (size_t)s * BH);
        }
    }
}

// Round 6
// 3454.598 us; speedup vs baseline: 15.4625x; 1.4393x over previous
//
#include <hip/hip_runtime.h>
#include <hip/hip_cooperative_groups.h>

namespace cg = cooperative_groups;

// 2-layer LSTM, S=512, B=32, H=1024, E=512.
// Round 6: layer-pipelined block specialization.
//   blocks 0..63  = layer 0, own 16 j-cols each, loop all 512 steps
//   blocks 64..127= layer 1, one step behind, consume h0(s) via LLC
// Communication: bf16 h-tiles in ws via agent-scope atomics (L2-bypass,
// proven round 5) + per-block step flags (64B apart, no atomicAdd
// contention). h0 ring depth 4 so L0 free-runs ahead; h1 ping-pong depth 2.
// Per-wave dependency gating: L1 waves 4..7 (h1-side K) start MFMAs while
// waves 0..3 poll for h0(s); L0 waves 0..1 (emb-side K) never poll.
// MFMA fragment/tile layout identical to verified rounds 4/5 (generalized
// to 4 N-tiles/block). Fallback: verified per-step kernel path.

#define S_LEN 512
#define BATCH 32
#define HID   1024
#define EMB   512
#define NBLK  128
#define NTHR  512

typedef short  bf16x8 __attribute__((ext_vector_type(8)));
typedef float  f32x4  __attribute__((ext_vector_type(4)));

union U8 { bf16x8 v; unsigned short us[8]; uint4 u4; unsigned long long ull[2]; };

__device__ __forceinline__ unsigned short f2bf(float f) {   // RNE f32->bf16
    unsigned u = __float_as_uint(f);
    u += 0x7fffu + ((u >> 16) & 1u);
    return (unsigned short)(u >> 16);
}

__device__ __forceinline__ uint4 pack8(float4 lo, float4 hi) {
    U8 r;
    r.us[0] = f2bf(lo.x); r.us[1] = f2bf(lo.y); r.us[2] = f2bf(lo.z); r.us[3] = f2bf(lo.w);
    r.us[4] = f2bf(hi.x); r.us[5] = f2bf(hi.y); r.us[6] = f2bf(hi.z); r.us[7] = f2bf(hi.w);
    return r.u4;
}

__device__ __forceinline__ f32x4 mfma16(bf16x8 a, bf16x8 b, f32x4 c) {
    return __builtin_amdgcn_mfma_f32_16x16x32_bf16(a, b, c, 0, 0, 0);
}

// agent-scope (LLC-coherent, L2-bypass) 16B load/store as 2x8B atomics
__device__ __forceinline__ U8 ld_ws16(const uint4* p) {
    const unsigned long long* q = (const unsigned long long*)p;
    U8 r;
    r.ull[0] = __hip_atomic_load(q,     __ATOMIC_RELAXED, __HIP_MEMORY_SCOPE_AGENT);
    r.ull[1] = __hip_atomic_load(q + 1, __ATOMIC_RELAXED, __HIP_MEMORY_SCOPE_AGENT);
    return r;
}
__device__ __forceinline__ void st_ws16(uint4* p, U8 v) {
    unsigned long long* q = (unsigned long long*)p;
    __hip_atomic_store(q,     v.ull[0], __ATOMIC_RELAXED, __HIP_MEMORY_SCOPE_AGENT);
    __hip_atomic_store(q + 1, v.ull[1], __ATOMIC_RELAXED, __HIP_MEMORY_SCOPE_AGENT);
}

__device__ __forceinline__ float sigm(float x) {
    return __builtin_amdgcn_rcpf(1.0f + __expf(-x));
}
__device__ __forceinline__ float tanh_fast(float x) {
    const float xc = fminf(fmaxf(x, -15.f), 15.f);
    const float t  = __expf(2.f * xc);
    return (t - 1.f) * __builtin_amdgcn_rcpf(t + 1.f);
}

// wave-parallel poll: lane l watches flags[l*16]; exit when ALL >= target
__device__ __forceinline__ void poll64(const int* flags, int target) {
    const int* p = flags + ((threadIdx.x & 63) << 4);
    for (;;) {
        const int v = __hip_atomic_load(p, __ATOMIC_RELAXED, __HIP_MEMORY_SCOPE_AGENT);
        if (__all(v >= target)) break;
        __builtin_amdgcn_s_sleep(1);
    }
}

__global__ __launch_bounds__(NTHR, 2)
void lstm_pipe(const int* __restrict__ x, const float* __restrict__ embed,
               const float* __restrict__ Wi0, const float* __restrict__ Wh0,
               const float* __restrict__ bi0, const float* __restrict__ bh0,
               const float* __restrict__ Wi1, const float* __restrict__ Wh1,
               const float* __restrict__ bi1, const float* __restrict__ bh1,
               const float* __restrict__ h0in, const float* __restrict__ c0in,
               float* __restrict__ outputs, float* __restrict__ hiddens,
               float* __restrict__ cells, uint4* __restrict__ ws)
{
    __shared__ f32x4 sRed[8][8][64];               // 64KB; aliased with sEmb
    __shared__ float sGates[32][68];
    __shared__ unsigned short sHex[32][16];
    __shared__ float sBias[16][4];
    uint4* sEmb = (uint4*)&sRed[0][0][0];          // 64*33 units (L0 only)

    const int tid  = threadIdx.x;
    const int lane = tid & 63;
    const int wv   = tid >> 6;                     // 0..7 = K-split wave
    const int bx   = blockIdx.x;
    const bool isL0 = (bx < 64);
    const int g    = isL0 ? bx : bx - 64;          // group-local block id

    uint4* h0base = ws;                            // 4 bufs x 4096 units
    uint4* h1base = ws + 16384;                    // 2 bufs x 4096 units
    int*   fbase  = (int*)(ws + 24576);            // f0[64], f1[64] @64B apart
    int*   flag0  = fbase;
    int*   flag1  = fbase + 1024;

    // ---- prepass: zero flags, init h tiles (plain stores + grid.sync) ----
    {
        const int gt = bx * NTHR + tid;
        if (gt < 2048) fbase[gt] = 0;
        if (gt < 8192) {                           // 2 layers x 128 kg x 32 b
            const int layer = gt >> 12, kg = (gt >> 5) & 127, b = gt & 31;
            const float* src = h0in + (((size_t)layer << 5) + b) * HID + (kg << 3);
            uint4* dst = layer ? (h1base + 4096) : (h0base + 3 * 4096);
            dst[(kg << 5) + b] = pack8(*(const float4*)src, *(const float4*)(src + 4));
        }
    }
    // ---- bias sums for this block's 16 columns ----
    if (tid < 16) {
        #pragma unroll
        for (int gate = 0; gate < 4; ++gate) {
            const int r = (gate << 10) + (g << 4) + tid;
            sBias[tid][gate] = isL0 ? (bi0[r] + bh0[r]) : (bi1[r] + bh1[r]);
        }
    }
    // ---- pointwise ownership: thread = (pb, pjj) ----
    const int pjj = tid & 15;
    const int pb  = tid >> 4;
    const int jg  = (g << 4) + pjj;
    float creg = isL0 ? c0in[(size_t)pb * HID + jg]
                      : c0in[(size_t)(BATCH + pb) * HID + jg];

    // ---- weight B-fragments into registers (verified layout, 4 N-tiles) ----
    // B-frag: lane l elem e = W[row(n)][kbase+ko+e], n=l&15, ko=(l>>4)*8,
    // row(n) = (n>>2)*1024 + g*16 + nt*4 + (n&3).
    const int n_    = lane & 15;
    const int ko_   = (lane >> 4) << 3;
    const int rb_   = ((n_ >> 2) << 10) + (g << 4) + (n_ & 3);
    bf16x8 w0[4][6];                               // L0 path only
    bf16x8 w1[4][8];                               // L1 path only
    if (isL0) {
        #pragma unroll
        for (int nt = 0; nt < 4; ++nt) {
            const int r = rb_ + (nt << 2);
            #pragma unroll
            for (int kf = 0; kf < 6; ++kf) {
                const int k = wv * 192 + kf * 32 + ko_;
                const float* src = (k < EMB) ? Wi0 + (size_t)r * EMB + k
                                             : Wh0 + (size_t)r * HID + (k - EMB);
                U8 t; t.u4 = pack8(*(const float4*)src, *(const float4*)(src + 4));
                w0[nt][kf] = t.v;
            }
        }
    } else {
        #pragma unroll
        for (int nt = 0; nt < 4; ++nt) {
            const int r = rb_ + (nt << 2);
            #pragma unroll
            for (int kf = 0; kf < 8; ++kf) {
                const int k = (wv << 8) + kf * 32 + ko_;
                const float* src = (k < HID) ? Wi1 + (size_t)r * HID + k
                                             : Wh1 + (size_t)r * HID + (k - HID);
                U8 t; t.u4 = pack8(*(const float4*)src, *(const float4*)(src + 4));
                w1[nt][kf] = t.v;
            }
        }
    }

    cg::grid_group grid = cg::this_grid();
    grid.sync();                                   // publish prepass, once

    const size_t BH = (size_t)BATCH * HID;

    if (isL0) {
        // ======================= LAYER-0 BLOCKS =======================
        for (int s = 0; s < S_LEN; ++s) {
            // stage emb(s): 32 rows x 512 f32 -> bf16 tiles in LDS
            const int* xs = x + (s << 5);
            #pragma unroll
            for (int it = 0; it < 4; ++it) {
                const int idx = tid + (it << 9);
                const int b = idx >> 6, kg = idx & 63;
                const float* src = embed + (size_t)xs[b] * EMB + (kg << 3);
                sEmb[kg * 33 + b] = pack8(*(const float4*)src, *(const float4*)(src + 4));
            }
            __syncthreads();                       // sEmb ready
            if (wv >= 2) poll64(flag0, s);         // h0(s-1) ready (waves 0-1 pure emb)

            const uint4* h0p = h0base + (((s + 3) & 3) << 12);
            f32x4 acc[2][4] = {{{0,0,0,0},{0,0,0,0},{0,0,0,0},{0,0,0,0}},
                               {{0,0,0,0},{0,0,0,0},{0,0,0,0},{0,0,0,0}}};
            #pragma unroll
            for (int kf = 0; kf < 6; ++kf) {
                const int kfg = wv * 6 + kf;       // 0..47
                bf16x8 a0, a1;
                if (kfg < 16) {                    // emb region
                    const int u = ((kfg << 2) + (lane >> 4)) * 33 + (lane & 15);
                    U8 t0; t0.u4 = sEmb[u];      a0 = t0.v;
                    U8 t1; t1.u4 = sEmb[u + 16]; a1 = t1.v;
                } else {                           // h0(s-1)
                    const int u = (((kfg - 16) << 2) + (lane >> 4)) * 32 + (lane & 15);
                    a0 = ld_ws16(&h0p[u]).v;
                    a1 = ld_ws16(&h0p[u + 16]).v;
                }
                #pragma unroll
                for (int nt = 0; nt < 4; ++nt) {
                    acc[0][nt] = mfma16(a0, w0[nt][kf], acc[0][nt]);
                    acc[1][nt] = mfma16(a1, w0[nt][kf], acc[1][nt]);
                }
            }
            __syncthreads();                       // sEmb reads done (alias sRed)
            #pragma unroll
            for (int mt = 0; mt < 2; ++mt)
                #pragma unroll
                for (int nt = 0; nt < 4; ++nt)
                    sRed[wv][(mt << 2) + nt][lane] = acc[mt][nt];
            __syncthreads();
            {   // K-split reduce: 512 threads, one (tile, lane) each
                const int tile = tid >> 6, l = tid & 63;
                f32x4 sum = sRed[0][tile][l];
                #pragma unroll
                for (int w = 1; w < 8; ++w) sum += sRed[w][tile][l];
                const int mt = tile >> 2, nt = tile & 3;
                const int b0 = (mt << 4) + ((l >> 4) << 2);
                const int col = (nt << 4) + (l & 15);
                sGates[b0 + 0][col] = sum[0];
                sGates[b0 + 1][col] = sum[1];
                sGates[b0 + 2][col] = sum[2];
                sGates[b0 + 3][col] = sum[3];
            }
            __syncthreads();
            {   // pointwise: thread (pb, pjj)
                const int cb = ((pjj >> 2) << 4) + (pjj & 3);
                const float ii = sigm     (sGates[pb][cb]      + sBias[pjj][0]);
                const float ff = sigm     (sGates[pb][cb + 4]  + sBias[pjj][1]);
                const float gg = tanh_fast(sGates[pb][cb + 8]  + sBias[pjj][2]);
                const float oo = sigm     (sGates[pb][cb + 12] + sBias[pjj][3]);
                const float cn = ff * creg + ii * gg;
                creg = cn;
                const float hn = oo * tanh_fast(cn);
                cells  [(size_t)(s << 1) * BH + (size_t)pb * HID + jg] = cn;
                hiddens[(size_t)(s << 1) * BH + (size_t)pb * HID + jg] = hn;
                sHex[pb][pjj] = f2bf(hn);
            }
            __syncthreads();
            if (wv == 0) {                         // publish h0(s)
                if (s >= 4) poll64(flag1, s - 3);  // ring-overwrite guard
                const int b = lane & 31, kgl = lane >> 5;
                U8 hb;
                #pragma unroll
                for (int jj = 0; jj < 8; ++jj) hb.us[jj] = sHex[b][(kgl << 3) + jj];
                st_ws16(h0base + ((s & 3) << 12) + (((g << 1) + kgl) << 5) + b, hb);
                asm volatile("s_waitcnt vmcnt(0)" ::: "memory");
                if (lane == 0)
                    __hip_atomic_store(flag0 + (g << 4), s + 1,
                                       __ATOMIC_RELAXED, __HIP_MEMORY_SCOPE_AGENT);
            }
        }
    } else {
        // ======================= LAYER-1 BLOCKS =======================
        for (int s = 0; s < S_LEN; ++s) {
            // per-wave gating: waves 0-3 need h0(s); waves 4-7 need h1(s-1)
            if (wv < 4) poll64(flag0, s + 1);
            else        poll64(flag1, s);

            const uint4* h0c = h0base + ((s & 3) << 12);
            const uint4* h1p = h1base + (((s + 1) & 1) << 12);
            f32x4 acc[2][4] = {{{0,0,0,0},{0,0,0,0},{0,0,0,0},{0,0,0,0}},
                               {{0,0,0,0},{0,0,0,0},{0,0,0,0},{0,0,0,0}}};
            #pragma unroll
            for (int kf = 0; kf < 8; ++kf) {
                const int kfg = (wv << 3) + kf;    // 0..63
                const uint4* src = (kfg < 32) ? h0c : h1p;
                const int kgb = (kfg < 32) ? (kfg << 2) : ((kfg - 32) << 2);
                const int u = (kgb + (lane >> 4)) * 32 + (lane & 15);
                const bf16x8 a0 = ld_ws16(&src[u]).v;
                const bf16x8 a1 = ld_ws16(&src[u + 16]).v;
                #pragma unroll
                for (int nt = 0; nt < 4; ++nt) {
                    acc[0][nt] = mfma16(a0, w1[nt][kf], acc[0][nt]);
                    acc[1][nt] = mfma16(a1, w1[nt][kf], acc[1][nt]);
                }
            }
            #pragma unroll
            for (int mt = 0; mt < 2; ++mt)
                #pragma unroll
                for (int nt = 0; nt < 4; ++nt)
                    sRed[wv][(mt << 2) + nt][lane] = acc[mt][nt];
            __syncthreads();
            {
                const int tile = tid >> 6, l = tid & 63;
                f32x4 sum = sRed[0][tile][l];
                #pragma unroll
                for (int w = 1; w < 8; ++w) sum += sRed[w][tile][l];
                const int mt = tile >> 2, nt = tile & 3;
                const int b0 = (mt << 4) + ((l >> 4) << 2);
                const int col = (nt << 4) + (l & 15);
                sGates[b0 + 0][col] = sum[0];
                sGates[b0 + 1][col] = sum[1];
                sGates[b0 + 2][col] = sum[2];
                sGates[b0 + 3][col] = sum[3];
            }
            __syncthreads();
            {   // pointwise + outputs
                const int cb = ((pjj >> 2) << 4) + (pjj & 3);
                const float ii = sigm     (sGates[pb][cb]      + sBias[pjj][0]);
                const float ff = sigm     (sGates[pb][cb + 4]  + sBias[pjj][1]);
                const float gg = tanh_fast(sGates[pb][cb + 8]  + sBias[pjj][2]);
                const float oo = sigm     (sGates[pb][cb + 12] + sBias[pjj][3]);
                const float cn = ff * creg + ii * gg;
                creg = cn;
                const float hn = oo * tanh_fast(cn);
                const size_t o = (size_t)pb * HID + jg;
                cells  [(size_t)((s << 1) + 1) * BH + o] = cn;
                hiddens[(size_t)((s << 1) + 1) * BH + o] = hn;
                outputs[(size_t)s * BH + o]              = hn;
                sHex[pb][pjj] = f2bf(hn);
            }
            __syncthreads();
            if (wv == 0) {                         // publish h1(s)
                const int b = lane & 31, kgl = lane >> 5;
                U8 hb;
                #pragma unroll
                for (int jj = 0; jj < 8; ++jj) hb.us[jj] = sHex[b][(kgl << 3) + jj];
                st_ws16(h1base + ((s & 1) << 12) + (((g << 1) + kgl) << 5) + b, hb);
                asm volatile("s_waitcnt vmcnt(0)" ::: "memory");
                if (lane == 0)
                    __hip_atomic_store(flag1 + (g << 4), s + 1,
                                       __ATOMIC_RELAXED, __HIP_MEMORY_SCOPE_AGENT);
            }
        }
    }
}

// ---------------- fallback: verified round-0 per-step kernel ----------------
#define KC 256
__global__ __launch_bounds__(256)
void lstm_step(const float* __restrict__ Wi, const float* __restrict__ Wh,
               const float* __restrict__ bi, const float* __restrict__ bh,
               const float* __restrict__ xsrc, const int* __restrict__ xidx, int K1,
               const float* __restrict__ Hprev, const float* __restrict__ Cprev,
               float* __restrict__ Hout, float* __restrict__ Cout,
               float* __restrict__ Hout2)
{
    __shared__ float As[32][KC + 4];
    __shared__ float red[256][5];

    const int t  = threadIdx.x;
    const int b  = t & 31;
    const int jl = (t >> 5) & 1;
    const int ks = t >> 6;
    const int j  = (blockIdx.x << 1) + jl;

    const int Ktot = K1 + HID;
    const int NC   = Ktot / KC;

    float acc0 = 0.f, acc1 = 0.f, acc2 = 0.f, acc3 = 0.f;

    for (int c = 0; c < NC; ++c) {
        const int  k0  = c * KC;
        const bool isX = (k0 < K1);

        #pragma unroll
        for (int i = 0; i < 8; ++i) {
            const int idx4 = t + (i << 8);
            const int row  = idx4 >> 6;
            const int c4   = idx4 & 63;
            const float* src;
            if (isX) {
                const size_t r0 = xidx ? (size_t)xidx[row] : (size_t)row;
                src = xsrc + r0 * (size_t)K1 + k0;
            } else {
                src = Hprev + (size_t)row * HID + (k0 - K1);
            }
            *(float4*)&As[row][c4 << 2] = *(const float4*)(src + (c4 << 2));
        }
        __syncthreads();

        const float* W      = isX ? Wi : Wh;
        const int    stride = isX ? K1 : HID;
        const int    kw     = k0 + (ks << 6) - (isX ? 0 : K1);
        const float* w0 = W + (size_t)(j       ) * stride + kw;
        const float* w1 = W + (size_t)(j + 1024) * stride + kw;
        const float* w2 = W + (size_t)(j + 2048) * stride + kw;
        const float* w3 = W + (size_t)(j + 3072) * stride + kw;
        const float* a  = &As[b][ks << 6];

        #pragma unroll 4
        for (int kk = 0; kk < 64; kk += 4) {
            const float4 av = *(const float4*)(a + kk);
            float4 w;
            w = *(const float4*)(w0 + kk);
            acc0 = fmaf(av.x, w.x, acc0); acc0 = fmaf(av.y, w.y, acc0);
            acc0 = fmaf(av.z, w.z, acc0); acc0 = fmaf(av.w, w.w, acc0);
            w = *(const float4*)(w1 + kk);
            acc1 = fmaf(av.x, w.x, acc1); acc1 = fmaf(av.y, w.y, acc1);
            acc1 = fmaf(av.z, w.z, acc1); acc1 = fmaf(av.w, w.w, acc1);
            w = *(const float4*)(w2 + kk);
            acc2 = fmaf(av.x, w.x, acc2); acc2 = fmaf(av.y, w.y, acc2);
            acc2 = fmaf(av.z, w.z, acc2); acc2 = fmaf(av.w, w.w, acc2);
            w = *(const float4*)(w3 + kk);
            acc3 = fmaf(av.x, w.x, acc3); acc3 = fmaf(av.y, w.y, acc3);
            acc3 = fmaf(av.z, w.z, acc3); acc3 = fmaf(av.w, w.w, acc3);
        }
        __syncthreads();
    }

    red[t][0] = acc0; red[t][1] = acc1; red[t][2] = acc2; red[t][3] = acc3;
    __syncthreads();

    if (t < 64) {
        float tot[4];
        #pragma unroll
        for (int gg = 0; gg < 4; ++gg) {
            const int r = j + (gg << 10);
            tot[gg] = red[t][gg] + red[t + 64][gg] + red[t + 128][gg] + red[t + 192][gg]
                   + bi[r] + bh[r];
        }
        const float ig = 1.f / (1.f + expf(-tot[0]));
        const float fg = 1.f / (1.f + expf(-tot[1]));
        const float gv = tanhf(tot[2]);
        const float og = 1.f / (1.f + expf(-tot[3]));
        const size_t o  = (size_t)b * HID + j;
        const float  cp = Cprev[o];
        const float  cn = fg * cp + ig * gv;
        const float  hn = og * tanhf(cn);
        Cout[o] = cn;
        Hout[o] = hn;
        if (Hout2) Hout2[o] = hn;
    }
}

extern "C" void kernel_launch(void* const* d_in, const int* in_sizes, int n_in,
                              void* d_out, int out_size, void* d_ws, size_t ws_size,
                              hipStream_t stream)
{
    (void)in_sizes; (void)n_in; (void)out_size;

    const int*   x     = (const int*)  d_in[0];
    const float* embed = (const float*)d_in[1];
    const float* Wi0   = (const float*)d_in[2];
    const float* Wh0   = (const float*)d_in[3];
    const float* bi0   = (const float*)d_in[4];
    const float* bh0   = (const float*)d_in[5];
    const float* Wi1   = (const float*)d_in[6];
    const float* Wh1   = (const float*)d_in[7];
    const float* bi1   = (const float*)d_in[8];
    const float* bh1   = (const float*)d_in[9];
    const float* h0in  = (const float*)d_in[10];
    const float* c0in  = (const float*)d_in[11];

    float* out     = (float*)d_out;
    const size_t BH = (size_t)BATCH * HID;              // 32768
    float* outputs = out;                               // (S,1,B,H)
    float* hiddens = out + (size_t)S_LEN * BH;          // (S,L,B,H)
    float* cells   = out + 3 * (size_t)S_LEN * BH;      // (S,L,B,H)
    uint4* ws      = (uint4*)d_ws;

    // ws: h0 ring 4x64KB | h1 ring 2x64KB | flags 8KB  = 401408 B
    bool coop_ok = (ws_size >= 401408);
    if (coop_ok) {
        void* args[] = {
            (void*)&x, (void*)&embed,
            (void*)&Wi0, (void*)&Wh0, (void*)&bi0, (void*)&bh0,
            (void*)&Wi1, (void*)&Wh1, (void*)&bi1, (void*)&bh1,
            (void*)&h0in, (void*)&c0in,
            (void*)&outputs, (void*)&hiddens, (void*)&cells, (void*)&ws
        };
        hipError_t e = hipLaunchCooperativeKernel((void*)lstm_pipe,
                                                  dim3(NBLK), dim3(NTHR), args, 0, stream);
        if (e != hipSuccess) { (void)hipGetLastError(); coop_ok = false; }
    }
    if (!coop_ok) {
        for (int s = 0; s < S_LEN; ++s) {
            const float* Hp0 = s ? hiddens + ((size_t)(s - 1) * 2 + 0) * BH : h0in;
            const float* Cp0 = s ? cells   + ((size_t)(s - 1) * 2 + 0) * BH : c0in;
            float* H0o = hiddens + ((size_t)s * 2 + 0) * BH;
            float* C0o = cells   + ((size_t)s * 2 + 0) * BH;
            lstm_step<<<512, 256, 0, stream>>>(Wi0, Wh0, bi0, bh0,
                                               embed, x + (size_t)s * BATCH, EMB,
                                               Hp0, Cp0, H0o, C0o, nullptr);

            const float* Hp1 = s ? hiddens + ((size_t)(s - 1) * 2 + 1) * BH : h0in + BH;
            const float* Cp1 = s ? cells   + ((size_t)(s - 1) * 2 + 1) * BH : c0in + BH;
            float* H1o = hiddens + ((size_t)s * 2 + 1) * BH;
            float* C1o = cells   + ((size_t)s * 2 + 1) * BH;
            lstm_step<<<512, 256, 0, stream>>>(Wi1, Wh1, bi1, bh1,
                                               H0o, nullptr, HID,
                                               Hp1, Cp1, H1o, C1o, outputs + (size_t)s * BH);
        }
    }
}